// Round 8
// baseline (414.741 us; speedup 1.0000x reference)
//
#include <hip/hip_runtime.h>
#include <math.h>

constexpr int FEAT = 128;   // DIN == DH == 128

typedef __attribute__((ext_vector_type(8))) short short8v;   // 8 bf16 raw
typedef __attribute__((ext_vector_type(4))) float f32x4;

// ---- fp32 -> bf16 (RNE) helpers ----
__device__ inline unsigned short f2bf(float f) {
    unsigned int u = __float_as_uint(f);
    u += 0x7fffu + ((u >> 16) & 1u);
    return (unsigned short)(u >> 16);
}
__device__ inline float bf2f(unsigned short h) {
    return __uint_as_float(((unsigned int)h) << 16);
}
__device__ inline void split8(const float4 v0, const float4 v1, short8v& h, short8v& lo) {
    const float* f = (const float*)&v0;
    unsigned short hh[8], ll[8];
    #pragma unroll
    for (int i = 0; i < 4; ++i) {
        hh[i] = f2bf(f[i]); ll[i] = f2bf(f[i] - bf2f(hh[i]));
    }
    const float* g = (const float*)&v1;
    #pragma unroll
    for (int i = 0; i < 4; ++i) {
        hh[4 + i] = f2bf(g[i]); ll[4 + i] = f2bf(g[i] - bf2f(hh[4 + i]));
    }
    h  = *(short8v*)hh;
    lo = *(short8v*)ll;
}

// ---------------- degree histogram (int) ----------------
__global__ void deg_kernel(const int* __restrict__ dst, int* __restrict__ degi, int E) {
    int e = blockIdx.x * 256 + threadIdx.x;
    if (e < E) atomicAdd(&degi[dst[e]], 1);
}

// ---------------- hierarchical exclusive scan (1024 elems / block) ----------------
__global__ __launch_bounds__(256) void blockred_kernel(const int* __restrict__ deg,
                                                       int* __restrict__ bsum, int n) {
    __shared__ int red[256];
    int base = blockIdx.x * 1024 + threadIdx.x * 4;
    int s = 0;
    if (base + 3 < n) {
        int4 v = *(const int4*)(deg + base);
        s = v.x + v.y + v.z + v.w;
    } else {
        for (int i = 0; i < 4; ++i) if (base + i < n) s += deg[base + i];
    }
    red[threadIdx.x] = s;
    __syncthreads();
    for (int st = 128; st > 0; st >>= 1) {
        if (threadIdx.x < st) red[threadIdx.x] += red[threadIdx.x + st];
        __syncthreads();
    }
    if (threadIdx.x == 0) bsum[blockIdx.x] = red[0];
}

// 1 block, 256 threads; nb <= 256 (N <= 262144)
__global__ __launch_bounds__(256) void scanb_kernel(const int* __restrict__ bsum,
                                                    int* __restrict__ bpre, int nb) {
    __shared__ int part[256];
    int t = threadIdx.x;
    int v = (t < nb) ? bsum[t] : 0;
    part[t] = v;
    __syncthreads();
    for (int s = 1; s < 256; s <<= 1) {
        int u = (t >= s) ? part[t - s] : 0;
        __syncthreads();
        part[t] += u;
        __syncthreads();
    }
    if (t < nb) bpre[t] = part[t] - v;
}

__global__ __launch_bounds__(256) void scanfill_kernel(const int* __restrict__ deg,
                                                       const int* __restrict__ bpre,
                                                       int* __restrict__ offs,
                                                       int* __restrict__ cur,
                                                       float* __restrict__ invd,
                                                       int n, int E) {
    __shared__ int part[256];
    int t = threadIdx.x;
    int base = blockIdx.x * 1024 + t * 4;
    int d[4];
    int s = 0;
    #pragma unroll
    for (int i = 0; i < 4; ++i) {
        d[i] = (base + i < n) ? deg[base + i] : 0;
        s += d[i];
    }
    part[t] = s;
    __syncthreads();
    for (int st = 1; st < 256; st <<= 1) {
        int u = (t >= st) ? part[t - st] : 0;
        __syncthreads();
        part[t] += u;
        __syncthreads();
    }
    int pre = bpre[blockIdx.x] + part[t] - s;
    #pragma unroll
    for (int i = 0; i < 4; ++i) {
        int idx = base + i;
        if (idx < n) {
            offs[idx] = pre;
            cur[idx]  = pre;
            invd[idx] = 1.0f / fmaxf((float)d[i], 1.0f);
            pre += d[i];
        }
    }
    if (blockIdx.x == 0 && t == 0) offs[n] = E;
}

// ---------------- CSR fill, dst-range partitioned (pass = blockIdx.y) ----------------
__global__ void fill_kernel(const int* __restrict__ src, const int* __restrict__ dst,
                            int* __restrict__ cur, int* __restrict__ eidx, int E) {
    int e = blockIdx.x * 256 + threadIdx.x;
    if (e >= E) return;
    int d = dst[e];
    if ((d >> 13) != (int)blockIdx.y) return;
    int pos = atomicAdd(&cur[d], 1);
    eidx[pos] = src[e];
}

// ---------------- W prep: split bf16 transpose WTh/WTl[c][k] of concat(Wl;Wr) ----------------
__global__ void prep_wt(const float* __restrict__ Wl, const float* __restrict__ Wr,
                        unsigned short* __restrict__ WTh, unsigned short* __restrict__ WTl,
                        int dout) {
    int idx = blockIdx.x * 256 + threadIdx.x;
    if (idx >= dout * 256) return;
    int c = idx >> 8;
    int k = idx & 255;
    float v = (k < 128) ? Wl[(size_t)k * dout + c] : Wr[(size_t)(k - 128) * dout + c];
    unsigned short h = f2bf(v);
    WTh[(size_t)c * 256 + k] = h;
    WTl[(size_t)c * 256 + k] = f2bf(v - bf2f(h));
}

// ---------------- fp32 -> bf16 convert (x -> xbf) ----------------
__global__ void f2bf_kernel(const float* __restrict__ in, unsigned short* __restrict__ out,
                            int total4) {
    int i = blockIdx.x * 256 + threadIdx.x;
    if (i >= total4) return;
    float4 v = *(const float4*)(in + (size_t)i * 4);
    ushort4 h;
    h.x = f2bf(v.x); h.y = f2bf(v.y); h.z = f2bf(v.z); h.w = f2bf(v.w);
    *(ushort4*)(out + (size_t)i * 4) = h;
}

// ---------------- gather mean from bf16 feats: one wave per node ----------------
__global__ __launch_bounds__(256) void gather_bf_kernel(const unsigned short* __restrict__ featbf,
                                                        const int* __restrict__ offs,
                                                        const int* __restrict__ eidx,
                                                        const float* __restrict__ invd,
                                                        float* __restrict__ agg, int n) {
    int node = blockIdx.x * 4 + (threadIdx.x >> 6);
    if (node >= n) return;
    int c = (threadIdx.x & 63) * 2;
    int beg = offs[node], end = offs[node + 1];
    float a0 = 0.f, a1 = 0.f;
    int j = beg;
    for (; j + 8 <= end; j += 8) {
        unsigned int v[8];
        #pragma unroll
        for (int q = 0; q < 8; ++q)
            v[q] = *(const unsigned int*)(featbf + (size_t)eidx[j + q] * FEAT + c);
        #pragma unroll
        for (int q = 0; q < 8; ++q) {
            a0 += __uint_as_float(v[q] << 16);
            a1 += __uint_as_float(v[q] & 0xffff0000u);
        }
    }
    for (; j < end; ++j) {
        unsigned int v = *(const unsigned int*)(featbf + (size_t)eidx[j] * FEAT + c);
        a0 += __uint_as_float(v << 16);
        a1 += __uint_as_float(v & 0xffff0000u);
    }
    float sc = invd[node];
    float2 r;
    r.x = a0 * sc;
    r.y = a1 * sc;
    *(float2*)(agg + (size_t)node * FEAT + c) = r;
}

// ---------------- MFMA dense, register-only, 16 rows/wave ----------------
// out = elu([mean|x] @ W + b); K=256. mean (fp32) uses bf16 hi/lo split (3 MFMAs);
// x is consumed as bf16 (2 MFMAs: xh*bh + xh*bl) from the bf16 activation copy.
// 64 rows/block, 4 waves x 16 rows -> 2x the waves of the 32-row version.
// If WBF: also write bf16 activation copy. If LSM: fuse log_softmax (DOUT=64).
// out may alias mean; outbf may alias xinbf: each wave reads only its own 16
// rows of mean/xinbf, all reads complete (vmcnt deps feed MFMAs) before its
// epilogue stores, and rows are wave-exclusive.
template <int DOUT, bool WBF, bool LSM>
__global__ __launch_bounds__(256) void dense_mfma(
    const float* mean, const unsigned short* xinbf,
    const unsigned short* __restrict__ WTh, const unsigned short* __restrict__ WTl,
    const float* __restrict__ bias,
    float* out, unsigned short* outbf, int n)
{
    constexpr int NCT = DOUT / 16;      // col tiles: 8 or 4
    const int tid  = threadIdx.x;
    const int l    = tid & 63;
    const int w    = tid >> 6;
    const int l15  = l & 15;
    const int lg   = l >> 4;
    const int row0 = blockIdx.x * 64 + w * 16;
    const int g    = row0 + l15;        // this lane's A row

    f32x4 acc[NCT];
    #pragma unroll
    for (int ct = 0; ct < NCT; ++ct)
        acc[ct] = (f32x4){0.f, 0.f, 0.f, 0.f};

    // ---- chunks 0..3: mean (fp32, hi/lo split, 3 MFMAs per ct) ----
    #pragma unroll
    for (int ch = 0; ch < 4; ++ch) {
        const int kb = ch * 32 + lg * 8;
        float4 v0 = make_float4(0.f, 0.f, 0.f, 0.f), v1 = v0;
        if (g < n) {
            const float* p = mean + (size_t)g * FEAT + kb;
            v0 = *(const float4*)p;
            v1 = *(const float4*)(p + 4);
        }
        short8v ah, al;
        split8(v0, v1, ah, al);
        #pragma unroll
        for (int ct = 0; ct < NCT; ++ct) {
            const size_t boff = (size_t)(ct * 16 + l15) * 256 + ch * 32 + lg * 8;
            short8v bh = *(const short8v*)(WTh + boff);
            short8v bl = *(const short8v*)(WTl + boff);
            acc[ct] = __builtin_amdgcn_mfma_f32_16x16x32_bf16(ah, bh, acc[ct], 0, 0, 0);
            acc[ct] = __builtin_amdgcn_mfma_f32_16x16x32_bf16(ah, bl, acc[ct], 0, 0, 0);
            acc[ct] = __builtin_amdgcn_mfma_f32_16x16x32_bf16(al, bh, acc[ct], 0, 0, 0);
        }
    }
    // ---- chunks 4..7: x as bf16 (2 MFMAs per ct) ----
    #pragma unroll
    for (int ch = 4; ch < 8; ++ch) {
        const int kb = (ch - 4) * 32 + lg * 8;
        short8v ah = (short8v){0,0,0,0,0,0,0,0};
        if (g < n) ah = *(const short8v*)(xinbf + (size_t)g * FEAT + kb);
        #pragma unroll
        for (int ct = 0; ct < NCT; ++ct) {
            const size_t boff = (size_t)(ct * 16 + l15) * 256 + ch * 32 + lg * 8;
            short8v bh = *(const short8v*)(WTh + boff);
            short8v bl = *(const short8v*)(WTl + boff);
            acc[ct] = __builtin_amdgcn_mfma_f32_16x16x32_bf16(ah, bh, acc[ct], 0, 0, 0);
            acc[ct] = __builtin_amdgcn_mfma_f32_16x16x32_bf16(ah, bl, acc[ct], 0, 0, 0);
        }
    }

    // ---- epilogue: bias + ELU (+ optional fused log_softmax) ----
    // C/D layout: col = ct*16 + l15, row(in-tile) = lg*4 + q
    float t[NCT][4];
    #pragma unroll
    for (int ct = 0; ct < NCT; ++ct) {
        float b = bias[ct * 16 + l15];
        #pragma unroll
        for (int q = 0; q < 4; ++q) {
            float v = acc[ct][q] + b;
            t[ct][q] = (v > 0.f) ? v : expm1f(v);
        }
    }
    if (LSM) {
        #pragma unroll
        for (int q = 0; q < 4; ++q) {
            float m = t[0][q];
            #pragma unroll
            for (int ct = 1; ct < NCT; ++ct) m = fmaxf(m, t[ct][q]);
            #pragma unroll
            for (int s = 1; s < 16; s <<= 1) m = fmaxf(m, __shfl_xor(m, s, 64));
            float sum = 0.f;
            #pragma unroll
            for (int ct = 0; ct < NCT; ++ct) sum += expf(t[ct][q] - m);
            #pragma unroll
            for (int s = 1; s < 16; s <<= 1) sum += __shfl_xor(sum, s, 64);
            float ls = m + logf(sum);
            #pragma unroll
            for (int ct = 0; ct < NCT; ++ct) t[ct][q] -= ls;
        }
    }
    #pragma unroll
    for (int ct = 0; ct < NCT; ++ct) {
        int col = ct * 16 + l15;
        #pragma unroll
        for (int q = 0; q < 4; ++q) {
            int grow = row0 + lg * 4 + q;
            if (grow < n) {
                out[(size_t)grow * DOUT + col] = t[ct][q];
                if (WBF) outbf[(size_t)grow * DOUT + col] = f2bf(t[ct][q]);
            }
        }
    }
}

extern "C" void kernel_launch(void* const* d_in, const int* in_sizes, int n_in,
                              void* d_out, int out_size, void* d_ws, size_t ws_size,
                              hipStream_t stream) {
    const float* x   = (const float*)d_in[0];
    const float* W1l = (const float*)d_in[1];
    const float* W1r = (const float*)d_in[2];
    const float* b1  = (const float*)d_in[3];
    const float* W2l = (const float*)d_in[4];
    const float* W2r = (const float*)d_in[5];
    const float* b2  = (const float*)d_in[6];
    const float* W3l = (const float*)d_in[7];
    const float* W3r = (const float*)d_in[8];
    const float* b3  = (const float*)d_in[9];
    const int*   src = (const int*)d_in[10];
    const int*   dst = (const int*)d_in[11];

    const int N = in_sizes[0] / FEAT;
    const int E = in_sizes[10];

    const size_t NA = ((size_t)N + 63) & ~(size_t)63;
    const size_t EA = ((size_t)E + 63) & ~(size_t)63;
    const int nb = (N + 1023) / 1024;       // scan blocks (<=256)
    const int npass = (N + 8191) >> 13;     // fill dst-range passes

    float* ws   = (float*)d_ws;
    float* invd = ws;                             // NA floats
    int*   deg  = (int*)(ws + NA);                // NA ints
    int*   offs = deg + NA;                       // NA+64 ints
    int*   cur  = offs + NA + 64;                 // NA ints
    int*   bsum = cur + NA;                       // 256 ints
    int*   bpre = bsum + 256;                     // 256 ints
    int*   eidx = bpre + 256;                     // EA ints
    unsigned short* wtb = (unsigned short*)(eidx + EA);
    unsigned short* WTh1 = wtb;                   // 128*256
    unsigned short* WTl1 = WTh1 + 128 * 256;
    unsigned short* WTh2 = WTl1 + 128 * 256;
    unsigned short* WTl2 = WTh2 + 128 * 256;
    unsigned short* WTh3 = WTl2 + 128 * 256;      // 64*256
    unsigned short* WTl3 = WTh3 + 64 * 256;
    float* bufA = (float*)(WTl3 + 64 * 256);      // NA*128 fp32
    float* bufB = bufA + NA * FEAT;               // NA*128 fp32
    unsigned short* hbf = (unsigned short*)(bufB + NA * FEAT);   // NA*128 bf16
    float* outp = (float*)d_out;

    const int gblocks = (N + 3) / 4;
    const int dblocks = (N + 63) / 64;

    // ---- CSR build + weight prep (once per launch) ----
    hipMemsetAsync(deg, 0, (size_t)N * 4, stream);
    deg_kernel<<<(E + 255) / 256, 256, 0, stream>>>(dst, deg, E);
    blockred_kernel<<<nb, 256, 0, stream>>>(deg, bsum, N);
    scanb_kernel<<<1, 256, 0, stream>>>(bsum, bpre, nb);
    scanfill_kernel<<<nb, 256, 0, stream>>>(deg, bpre, offs, cur, invd, N, E);
    fill_kernel<<<dim3((E + 255) / 256, npass), 256, 0, stream>>>(src, dst, cur, eidx, E);
    prep_wt<<<(128 * 256 + 255) / 256, 256, 0, stream>>>(W1l, W1r, WTh1, WTl1, 128);
    prep_wt<<<(128 * 256 + 255) / 256, 256, 0, stream>>>(W2l, W2r, WTh2, WTl2, 128);
    prep_wt<<<(64 * 256 + 255) / 256, 256, 0, stream>>>(W3l, W3r, WTh3, WTl3, 64);
    f2bf_kernel<<<(N * FEAT / 4 + 255) / 256, 256, 0, stream>>>(x, hbf, N * FEAT / 4);

    // layer 1: gather(xbf) -> A ; h1 = dense(A, xbf) -> A (fp32) + hbf (bf16, in place over xbf)
    gather_bf_kernel<<<gblocks, 256, 0, stream>>>(hbf, offs, eidx, invd, bufA, N);
    dense_mfma<128, true, false><<<dblocks, 256, 0, stream>>>(bufA, hbf, WTh1, WTl1, b1, bufA, hbf, N);

    // layer 2: gather(h1bf) -> B ; h2 = dense(B, h1bf) -> B (fp32) + hbf (bf16)
    gather_bf_kernel<<<gblocks, 256, 0, stream>>>(hbf, offs, eidx, invd, bufB, N);
    dense_mfma<128, true, false><<<dblocks, 256, 0, stream>>>(bufB, hbf, WTh2, WTl2, b2, bufB, hbf, N);

    // layer 3: gather(h2bf) -> A ; out = log_softmax(elu(dense(A, h2bf))) -> d_out (fused)
    gather_bf_kernel<<<gblocks, 256, 0, stream>>>(hbf, offs, eidx, invd, bufA, N);
    dense_mfma<64, false, true><<<dblocks, 256, 0, stream>>>(bufA, hbf, WTh3, WTl3, b3, outp, nullptr, N);
}

// Round 9
// 283.581 us; speedup vs baseline: 1.4625x; 1.4625x over previous
//
#include <hip/hip_runtime.h>
#include <math.h>

constexpr int FEAT = 128;   // DIN == DH == 128

typedef __attribute__((ext_vector_type(8))) short short8v;   // 8 bf16 raw / 16 B
typedef __attribute__((ext_vector_type(4))) float f32x4;

// ---- fp32 -> bf16 (RNE) helpers ----
__device__ inline unsigned short f2bf(float f) {
    unsigned int u = __float_as_uint(f);
    u += 0x7fffu + ((u >> 16) & 1u);
    return (unsigned short)(u >> 16);
}
__device__ inline float bf2f(unsigned short h) {
    return __uint_as_float(((unsigned int)h) << 16);
}
__device__ inline void split8(const float4 v0, const float4 v1, short8v& h, short8v& lo) {
    const float* f = (const float*)&v0;
    unsigned short hh[8], ll[8];
    #pragma unroll
    for (int i = 0; i < 4; ++i) {
        hh[i] = f2bf(f[i]); ll[i] = f2bf(f[i] - bf2f(hh[i]));
    }
    const float* g = (const float*)&v1;
    #pragma unroll
    for (int i = 0; i < 4; ++i) {
        hh[4 + i] = f2bf(g[i]); ll[4 + i] = f2bf(g[i] - bf2f(hh[4 + i]));
    }
    h  = *(short8v*)hh;
    lo = *(short8v*)ll;
}

// ---------------- degree histogram (int) ----------------
__global__ void deg_kernel(const int* __restrict__ dst, int* __restrict__ degi, int E) {
    int e = blockIdx.x * 256 + threadIdx.x;
    if (e < E) atomicAdd(&degi[dst[e]], 1);
}

// ---------------- hierarchical exclusive scan (1024 elems / block) ----------------
__global__ __launch_bounds__(256) void blockred_kernel(const int* __restrict__ deg,
                                                       int* __restrict__ bsum, int n) {
    __shared__ int red[256];
    int base = blockIdx.x * 1024 + threadIdx.x * 4;
    int s = 0;
    if (base + 3 < n) {
        int4 v = *(const int4*)(deg + base);
        s = v.x + v.y + v.z + v.w;
    } else {
        for (int i = 0; i < 4; ++i) if (base + i < n) s += deg[base + i];
    }
    red[threadIdx.x] = s;
    __syncthreads();
    for (int st = 128; st > 0; st >>= 1) {
        if (threadIdx.x < st) red[threadIdx.x] += red[threadIdx.x + st];
        __syncthreads();
    }
    if (threadIdx.x == 0) bsum[blockIdx.x] = red[0];
}

// 1 block, 256 threads; nb <= 256 (N <= 262144)
__global__ __launch_bounds__(256) void scanb_kernel(const int* __restrict__ bsum,
                                                    int* __restrict__ bpre, int nb) {
    __shared__ int part[256];
    int t = threadIdx.x;
    int v = (t < nb) ? bsum[t] : 0;
    part[t] = v;
    __syncthreads();
    for (int s = 1; s < 256; s <<= 1) {
        int u = (t >= s) ? part[t - s] : 0;
        __syncthreads();
        part[t] += u;
        __syncthreads();
    }
    if (t < nb) bpre[t] = part[t] - v;
}

__global__ __launch_bounds__(256) void scanfill_kernel(const int* __restrict__ deg,
                                                       const int* __restrict__ bpre,
                                                       int* __restrict__ offs,
                                                       int* __restrict__ cur,
                                                       float* __restrict__ invd,
                                                       int n, int E) {
    __shared__ int part[256];
    int t = threadIdx.x;
    int base = blockIdx.x * 1024 + t * 4;
    int d[4];
    int s = 0;
    #pragma unroll
    for (int i = 0; i < 4; ++i) {
        d[i] = (base + i < n) ? deg[base + i] : 0;
        s += d[i];
    }
    part[t] = s;
    __syncthreads();
    for (int st = 1; st < 256; st <<= 1) {
        int u = (t >= st) ? part[t - st] : 0;
        __syncthreads();
        part[t] += u;
        __syncthreads();
    }
    int pre = bpre[blockIdx.x] + part[t] - s;
    #pragma unroll
    for (int i = 0; i < 4; ++i) {
        int idx = base + i;
        if (idx < n) {
            offs[idx] = pre;
            cur[idx]  = pre;
            invd[idx] = 1.0f / fmaxf((float)d[i], 1.0f);
            pre += d[i];
        }
    }
    if (blockIdx.x == 0 && t == 0) offs[n] = E;
}

// ---------------- CSR fill, dst-range partitioned (pass = blockIdx.y) ----------------
__global__ void fill_kernel(const int* __restrict__ src, const int* __restrict__ dst,
                            int* __restrict__ cur, int* __restrict__ eidx, int E) {
    int e = blockIdx.x * 256 + threadIdx.x;
    if (e >= E) return;
    int d = dst[e];
    if ((d >> 13) != (int)blockIdx.y) return;
    int pos = atomicAdd(&cur[d], 1);
    eidx[pos] = src[e];
}

// ---------------- W prep: split bf16 transpose WTh/WTl[c][k] of concat(Wl;Wr) ----------------
__global__ void prep_wt(const float* __restrict__ Wl, const float* __restrict__ Wr,
                        unsigned short* __restrict__ WTh, unsigned short* __restrict__ WTl,
                        int dout) {
    int idx = blockIdx.x * 256 + threadIdx.x;
    if (idx >= dout * 256) return;
    int c = idx >> 8;
    int k = idx & 255;
    float v = (k < 128) ? Wl[(size_t)k * dout + c] : Wr[(size_t)(k - 128) * dout + c];
    unsigned short h = f2bf(v);
    WTh[(size_t)c * 256 + k] = h;
    WTl[(size_t)c * 256 + k] = f2bf(v - bf2f(h));
}

// ---------------- fp32 -> bf16 convert (x -> xbf) ----------------
__global__ void f2bf_kernel(const float* __restrict__ in, unsigned short* __restrict__ out,
                            int total4) {
    int i = blockIdx.x * 256 + threadIdx.x;
    if (i >= total4) return;
    float4 v = *(const float4*)(in + (size_t)i * 4);
    ushort4 h;
    h.x = f2bf(v.x); h.y = f2bf(v.y); h.z = f2bf(v.z); h.w = f2bf(v.w);
    *(ushort4*)(out + (size_t)i * 4) = h;
}

// ---------------- gather mean from bf16 feats: one wave per node ----------------
__global__ __launch_bounds__(256) void gather_bf_kernel(const unsigned short* __restrict__ featbf,
                                                        const int* __restrict__ offs,
                                                        const int* __restrict__ eidx,
                                                        const float* __restrict__ invd,
                                                        float* __restrict__ agg, int n) {
    int node = blockIdx.x * 4 + (threadIdx.x >> 6);
    if (node >= n) return;
    int c = (threadIdx.x & 63) * 2;
    int beg = offs[node], end = offs[node + 1];
    float a0 = 0.f, a1 = 0.f;
    int j = beg;
    for (; j + 8 <= end; j += 8) {
        unsigned int v[8];
        #pragma unroll
        for (int q = 0; q < 8; ++q)
            v[q] = *(const unsigned int*)(featbf + (size_t)eidx[j + q] * FEAT + c);
        #pragma unroll
        for (int q = 0; q < 8; ++q) {
            a0 += __uint_as_float(v[q] << 16);
            a1 += __uint_as_float(v[q] & 0xffff0000u);
        }
    }
    for (; j < end; ++j) {
        unsigned int v = *(const unsigned int*)(featbf + (size_t)eidx[j] * FEAT + c);
        a0 += __uint_as_float(v << 16);
        a1 += __uint_as_float(v & 0xffff0000u);
    }
    float sc = invd[node];
    float2 r;
    r.x = a0 * sc;
    r.y = a1 * sc;
    *(float2*)(agg + (size_t)node * FEAT + c) = r;
}

// ---------------- MFMA dense, LDS-resident B, 64 cols/block ----------------
// out = elu([mean|x] @ W + b); K=256. mean (fp32): hi/lo split, 3 MFMAs;
// x (bf16): 2 MFMAs (xh*bh + xh*bl). Block = 1024 thr = 16 waves x 16 rows
// = 256 rows; blockIdx.y = 64-col half (DOUT=128) or 0 (DOUT=64).
// B staged ONCE into LDS (64 KB hi+lo) with XOR swizzle byte^=((c&7)<<4)
// (row stride 512 B -> 2-way bank aliasing only), one barrier total.
// WBF=true: store ONLY the bf16 activation copy (fp32 h1/h2 is dead).
// WBF=false: store fp32 (+ fused log_softmax if LSM; requires DOUT=64).
template <int DOUT, bool WBF, bool LSM>
__global__ __launch_bounds__(1024, 4) void dense_mfma(
    const float* __restrict__ mean, const unsigned short* __restrict__ xinbf,
    const unsigned short* __restrict__ WTh, const unsigned short* __restrict__ WTl,
    const float* __restrict__ bias,
    float* outf, unsigned short* outbf, int n)
{
    __shared__ unsigned short Bh[64 * 256];   // 32 KB
    __shared__ unsigned short Bl[64 * 256];   // 32 KB
    const int tid = threadIdx.x;
    const int colbase = blockIdx.y * 64;

    // ---- stage B (64 cols x 256 k, hi+lo), swizzled ----
    #pragma unroll
    for (int it = 0; it < 2; ++it) {
        int o  = (tid + it * 1024) * 8;       // ushort index, 16B granules
        int cl = o >> 8;                      // local col 0..63
        int k  = o & 255;
        size_t gsrc = (size_t)(colbase + cl) * 256 + k;
        int db = (o * 2) ^ ((cl & 7) << 4);   // swizzled byte offset
        *(short8v*)((char*)Bh + db) = *(const short8v*)(WTh + gsrc);
        *(short8v*)((char*)Bl + db) = *(const short8v*)(WTl + gsrc);
    }
    __syncthreads();

    const int l    = tid & 63;
    const int w    = tid >> 6;
    const int l15  = l & 15;
    const int lg   = l >> 4;
    const int row0 = blockIdx.x * 256 + w * 16;
    if (row0 >= n) return;                    // no barriers after this point
    const int g = row0 + l15;                 // this lane's A row

    f32x4 acc[4];
    #pragma unroll
    for (int ct = 0; ct < 4; ++ct) acc[ct] = (f32x4){0.f, 0.f, 0.f, 0.f};

    // ---- chunks 0..3: mean (fp32, hi/lo split, 3 MFMAs per ct) ----
    #pragma unroll
    for (int ch = 0; ch < 4; ++ch) {
        float4 v0 = make_float4(0.f, 0.f, 0.f, 0.f), v1 = v0;
        if (g < n) {
            const float* p = mean + (size_t)g * FEAT + ch * 32 + lg * 8;
            v0 = *(const float4*)p;
            v1 = *(const float4*)(p + 4);
        }
        short8v ah, al;
        split8(v0, v1, ah, al);
        #pragma unroll
        for (int ct = 0; ct < 4; ++ct) {
            int cl = ct * 16 + l15;
            int db = (cl * 512 + ch * 64 + lg * 16) ^ ((cl & 7) << 4);
            short8v bh = *(const short8v*)((const char*)Bh + db);
            short8v bl = *(const short8v*)((const char*)Bl + db);
            acc[ct] = __builtin_amdgcn_mfma_f32_16x16x32_bf16(ah, bh, acc[ct], 0, 0, 0);
            acc[ct] = __builtin_amdgcn_mfma_f32_16x16x32_bf16(ah, bl, acc[ct], 0, 0, 0);
            acc[ct] = __builtin_amdgcn_mfma_f32_16x16x32_bf16(al, bh, acc[ct], 0, 0, 0);
        }
    }
    // ---- chunks 4..7: x as bf16 (2 MFMAs per ct) ----
    #pragma unroll
    for (int ch = 4; ch < 8; ++ch) {
        short8v ah = (short8v){0,0,0,0,0,0,0,0};
        if (g < n) ah = *(const short8v*)(xinbf + (size_t)g * FEAT + (ch - 4) * 32 + lg * 8);
        #pragma unroll
        for (int ct = 0; ct < 4; ++ct) {
            int cl = ct * 16 + l15;
            int db = (cl * 512 + ch * 64 + lg * 16) ^ ((cl & 7) << 4);
            short8v bh = *(const short8v*)((const char*)Bh + db);
            short8v bl = *(const short8v*)((const char*)Bl + db);
            acc[ct] = __builtin_amdgcn_mfma_f32_16x16x32_bf16(ah, bh, acc[ct], 0, 0, 0);
            acc[ct] = __builtin_amdgcn_mfma_f32_16x16x32_bf16(ah, bl, acc[ct], 0, 0, 0);
        }
    }

    // ---- epilogue: bias + ELU (+ optional fused log_softmax) ----
    // C/D layout: col = ct*16 + l15, row(in-tile) = lg*4 + q
    float t[4][4];
    #pragma unroll
    for (int ct = 0; ct < 4; ++ct) {
        float b = bias[colbase + ct * 16 + l15];
        #pragma unroll
        for (int q = 0; q < 4; ++q) {
            float v = acc[ct][q] + b;
            t[ct][q] = (v > 0.f) ? v : expm1f(v);
        }
    }
    if (LSM) {
        #pragma unroll
        for (int q = 0; q < 4; ++q) {
            float m = t[0][q];
            #pragma unroll
            for (int ct = 1; ct < 4; ++ct) m = fmaxf(m, t[ct][q]);
            #pragma unroll
            for (int s = 1; s < 16; s <<= 1) m = fmaxf(m, __shfl_xor(m, s, 64));
            float sum = 0.f;
            #pragma unroll
            for (int ct = 0; ct < 4; ++ct) sum += expf(t[ct][q] - m);
            #pragma unroll
            for (int s = 1; s < 16; s <<= 1) sum += __shfl_xor(sum, s, 64);
            float ls = m + logf(sum);
            #pragma unroll
            for (int ct = 0; ct < 4; ++ct) t[ct][q] -= ls;
        }
    }
    #pragma unroll
    for (int ct = 0; ct < 4; ++ct) {
        int col = colbase + ct * 16 + l15;
        #pragma unroll
        for (int q = 0; q < 4; ++q) {
            int grow = row0 + lg * 4 + q;
            if (grow < n) {
                if (WBF) outbf[(size_t)grow * DOUT + col] = f2bf(t[ct][q]);
                else     outf[(size_t)grow * DOUT + col] = t[ct][q];
            }
        }
    }
}

extern "C" void kernel_launch(void* const* d_in, const int* in_sizes, int n_in,
                              void* d_out, int out_size, void* d_ws, size_t ws_size,
                              hipStream_t stream) {
    const float* x   = (const float*)d_in[0];
    const float* W1l = (const float*)d_in[1];
    const float* W1r = (const float*)d_in[2];
    const float* b1  = (const float*)d_in[3];
    const float* W2l = (const float*)d_in[4];
    const float* W2r = (const float*)d_in[5];
    const float* b2  = (const float*)d_in[6];
    const float* W3l = (const float*)d_in[7];
    const float* W3r = (const float*)d_in[8];
    const float* b3  = (const float*)d_in[9];
    const int*   src = (const int*)d_in[10];
    const int*   dst = (const int*)d_in[11];

    const int N = in_sizes[0] / FEAT;
    const int E = in_sizes[10];

    const size_t NA = ((size_t)N + 63) & ~(size_t)63;
    const size_t EA = ((size_t)E + 63) & ~(size_t)63;
    const int nb = (N + 1023) / 1024;       // scan blocks (<=256)
    const int npass = (N + 8191) >> 13;     // fill dst-range passes

    float* ws   = (float*)d_ws;
    float* invd = ws;                             // NA floats
    int*   deg  = (int*)(ws + NA);                // NA ints
    int*   offs = deg + NA;                       // NA+64 ints
    int*   cur  = offs + NA + 64;                 // NA ints
    int*   bsum = cur + NA;                       // 256 ints
    int*   bpre = bsum + 256;                     // 256 ints
    int*   eidx = bpre + 256;                     // EA ints
    unsigned short* wtb = (unsigned short*)(eidx + EA);
    unsigned short* WTh1 = wtb;                   // 128*256
    unsigned short* WTl1 = WTh1 + 128 * 256;
    unsigned short* WTh2 = WTl1 + 128 * 256;
    unsigned short* WTl2 = WTh2 + 128 * 256;
    unsigned short* WTh3 = WTl2 + 128 * 256;      // 64*256
    unsigned short* WTl3 = WTh3 + 64 * 256;
    float* bufM = (float*)(WTl3 + 64 * 256);      // NA*128 fp32 mean scratch
    unsigned short* bfA = (unsigned short*)(bufM + NA * FEAT);  // NA*128 bf16
    unsigned short* bfB = bfA + NA * FEAT;                      // NA*128 bf16
    float* outp = (float*)d_out;

    const int gblocks = (N + 3) / 4;
    const int dblocks = (N + 255) / 256;

    // ---- CSR build + weight prep (once per launch) ----
    hipMemsetAsync(deg, 0, (size_t)N * 4, stream);
    deg_kernel<<<(E + 255) / 256, 256, 0, stream>>>(dst, deg, E);
    blockred_kernel<<<nb, 256, 0, stream>>>(deg, bsum, N);
    scanb_kernel<<<1, 256, 0, stream>>>(bsum, bpre, nb);
    scanfill_kernel<<<nb, 256, 0, stream>>>(deg, bpre, offs, cur, invd, N, E);
    fill_kernel<<<dim3((E + 255) / 256, npass), 256, 0, stream>>>(src, dst, cur, eidx, E);
    prep_wt<<<(128 * 256 + 255) / 256, 256, 0, stream>>>(W1l, W1r, WTh1, WTl1, 128);
    prep_wt<<<(128 * 256 + 255) / 256, 256, 0, stream>>>(W2l, W2r, WTh2, WTl2, 128);
    prep_wt<<<(64 * 256 + 255) / 256, 256, 0, stream>>>(W3l, W3r, WTh3, WTl3, 64);
    f2bf_kernel<<<(N * FEAT / 4 + 255) / 256, 256, 0, stream>>>(x, bfA, N * FEAT / 4);

    // layer 1: gather(xbf=bfA) -> M ; h1bf = dense(M, bfA) -> bfB
    gather_bf_kernel<<<gblocks, 256, 0, stream>>>(bfA, offs, eidx, invd, bufM, N);
    dense_mfma<128, true, false><<<dim3(dblocks, 2), 1024, 0, stream>>>(bufM, bfA, WTh1, WTl1, b1, nullptr, bfB, N);

    // layer 2: gather(h1bf=bfB) -> M ; h2bf = dense(M, bfB) -> bfA
    gather_bf_kernel<<<gblocks, 256, 0, stream>>>(bfB, offs, eidx, invd, bufM, N);
    dense_mfma<128, true, false><<<dim3(dblocks, 2), 1024, 0, stream>>>(bufM, bfB, WTh2, WTl2, b2, nullptr, bfA, N);

    // layer 3: gather(h2bf=bfA) -> M ; out = log_softmax(elu(dense(M, bfA))) -> d_out
    gather_bf_kernel<<<gblocks, 256, 0, stream>>>(bfA, offs, eidx, invd, bufM, N);
    dense_mfma<64, false, true><<<dim3(dblocks, 1), 1024, 0, stream>>>(bufM, bfA, WTh3, WTl3, b3, outp, nullptr, N);
}